// Round 9
// baseline (102.058 us; speedup 1.0000x reference)
//
#include <hip/hip_runtime.h>
#include <hip/hip_bf16.h>

// ---- types ----
typedef __attribute__((ext_vector_type(8))) short bf16x8;   // 8 bf16 in 4 VGPRs (MFMA A/B frag)
typedef __attribute__((ext_vector_type(4))) float f32x4;    // MFMA C/D frag
typedef __attribute__((ext_vector_type(4))) short s16x4;

#define DM 512
#define T_SEQ 512
#define NSEQ 32         // B*S = 2*16
#define MROWS 16384     // NSEQ * T_SEQ
#define QKV_DIM 768
#define HD 64
#define NEG_INF_F (-1000000000.0f)
#define LOG2E 1.44269504088896340736f

// f32 -> bf16 bits, round-to-nearest-even (software)
__device__ __forceinline__ short f2bf(float f) {
    unsigned int u = __builtin_bit_cast(unsigned int, f);
    unsigned int r = (u + 0x7FFFu + ((u >> 16) & 1u)) >> 16;
    return (short)r;
}

// HW convert (v_cvt path)
__device__ __forceinline__ short f2bf_hw(float f) {
    __hip_bfloat16 h = __float2bfloat16(f);
    return __builtin_bit_cast(short, h);
}

__device__ __forceinline__ void gload16(const void* g, void* l) {
    __builtin_amdgcn_global_load_lds(
        (const __attribute__((address_space(1))) void*)g,
        (__attribute__((address_space(3))) void*)l, 16, 0, 0);
}

// ---------------- kernel 0: weight converts + rope table (xt pass ELIMINATED) ----------
__global__ __launch_bounds__(128) void k_convert(
    const float* __restrict__ qkvw, const float* __restrict__ owf,
    short* __restrict__ qw, short* __restrict__ ow,
    float* __restrict__ cosT, float* __restrict__ sinT)
{
    int bidx = blockIdx.x, tid = threadIdx.x;
    if (bidx < 1280) {
        int wr = bidx;
        const float* src; short* dst;
        if (wr < QKV_DIM) { src = qkvw + (size_t)wr * 512; dst = qw + (size_t)wr * 512; }
        else             { src = owf + (size_t)(wr - QKV_DIM) * 512; dst = ow + (size_t)(wr - QKV_DIM) * 512; }
        float4 v = *(const float4*)(src + tid * 4);
        s16x4 o; o.x = f2bf(v.x); o.y = f2bf(v.y); o.z = f2bf(v.z); o.w = f2bf(v.w);
        *(s16x4*)(dst + tid * 4) = o;
    } else {
        int idx = (bidx - 1280) * 128 + tid;   // 0..16383 = t*32+d
        int t = idx >> 5, d = idx & 31;
        float inv = powf(10000.0f, -(float)d * (1.0f / 32.0f));
        float ang = (float)t * inv;
        float sv, cv; sincosf(ang, &sv, &cv);
        cosT[idx] = cv; sinT[idx] = sv;
    }
}

// ------- shared GEMM mainloop (bf16 A,B): 128x128 tile, BK=32, 4 waves, dbuf -------
__device__ __forceinline__ void gemm_mainloop_db(
    const short* __restrict__ Ab, const short* __restrict__ Bb, int K,
    short* As0, short* As1, short* Bs0, short* Bs1,
    int wave, int lane, f32x4 acc[4][4])
{
    int wr = (wave >> 1) * 64, wc = (wave & 1) * 64;
    int cl = lane & 15, g = lane >> 4;
    auto stg = [&](int kt, short* As, short* Bs) {
        #pragma unroll
        for (int c = 0; c < 2; ++c) {
            int chunk = (wave * 2 + c) * 64 + lane;
            int row = chunk >> 2, kc = chunk & 3;
            gload16(Ab + (size_t)row * K + kt + kc * 8, As + (wave * 2 + c) * 512);
            gload16(Bb + (size_t)row * K + kt + kc * 8, Bs + (wave * 2 + c) * 512);
        }
    };
    stg(0, As0, Bs0);
    for (int kt = 0; kt < K; kt += 32) {
        short* Asc = (kt & 32) ? As1 : As0;
        short* Bsc = (kt & 32) ? Bs1 : Bs0;
        short* Asn = (kt & 32) ? As0 : As1;
        short* Bsn = (kt & 32) ? Bs0 : Bs1;
        __syncthreads();                 // drains vmcnt -> current buf ready, prev reads done
        if (kt + 32 < K) stg(kt + 32, Asn, Bsn);
        bf16x8 af[4], bg[4];
        #pragma unroll
        for (int mf = 0; mf < 4; ++mf)
            af[mf] = *(const bf16x8*)(Asc + (wr + mf * 16 + cl) * 32 + (g << 3));
        #pragma unroll
        for (int nf = 0; nf < 4; ++nf)
            bg[nf] = *(const bf16x8*)(Bsc + (wc + nf * 16 + cl) * 32 + (g << 3));
        #pragma unroll
        for (int mf = 0; mf < 4; ++mf)
            #pragma unroll
            for (int nf = 0; nf < 4; ++nf)
                acc[mf][nf] = __builtin_amdgcn_mfma_f32_16x16x32_bf16(af[mf], bg[nf], acc[mf][nf], 0, 0, 0);
    }
}

// ---------------- kernel 1: QKV GEMM (A direct from f32 x, reg-staged) + RoPE epilogue --
// A-staging: per lane 2x float4 load -> v_cvt x8 -> ds_write_b128 (conversion forces
// reg-staging; layout transform (b,t,s)->m folded into prologue row pointers).
// Q pre-scaled by 0.125*log2(e). V written TRANSPOSED vtb[n,g][d][t] via per-wave LDS tile.
__global__ __launch_bounds__(256) void k_gemm_qkv(
    const float* __restrict__ x, const short* __restrict__ qw,
    const float* __restrict__ cosT, const float* __restrict__ sinT,
    short* __restrict__ qb, short* __restrict__ kb, short* __restrict__ vtb)
{
    __shared__ short As0[128 * 32], As1[128 * 32], Bs0[128 * 32], Bs1[128 * 32];
    __shared__ short Vld[4][16 * 64];   // per-wave transpose tile [d][t], 2KB each
    int tid = threadIdx.x, wave = tid >> 6, lane = tid & 63;
    int cl = lane & 15, g = lane >> 4;
    int bm = blockIdx.x, bn = blockIdx.y;
    const short* Bb = qw + (size_t)bn * 128 * 512;

    // prologue: per-chunk A row pointers (fixed across K)
    const float* xrowp[2];
    int choff[2];
    #pragma unroll
    for (int c = 0; c < 2; ++c) {
        int chunk = (wave * 2 + c) * 64 + lane;
        int row = chunk >> 2, kc = chunk & 3;
        int m = bm * 128 + row, n = m >> 9, t = m & 511, b = n >> 4, s = n & 15;
        xrowp[c] = x + ((size_t)((b * 512 + t) * 16 + s)) * 512 + kc * 8;
        choff[c] = chunk * 8;
    }
    auto stgA = [&](int kt, short* As) {
        #pragma unroll
        for (int c = 0; c < 2; ++c) {
            float4 fa = *(const float4*)(xrowp[c] + kt);
            float4 fb = *(const float4*)(xrowp[c] + kt + 4);
            bf16x8 v;
            v[0] = f2bf_hw(fa.x); v[1] = f2bf_hw(fa.y); v[2] = f2bf_hw(fa.z); v[3] = f2bf_hw(fa.w);
            v[4] = f2bf_hw(fb.x); v[5] = f2bf_hw(fb.y); v[6] = f2bf_hw(fb.z); v[7] = f2bf_hw(fb.w);
            *(bf16x8*)(As + choff[c]) = v;
        }
    };
    auto stgB = [&](int kt, short* Bs) {
        #pragma unroll
        for (int c = 0; c < 2; ++c) {
            int chunk = (wave * 2 + c) * 64 + lane;
            int row = chunk >> 2, kc = chunk & 3;
            gload16(Bb + (size_t)row * 512 + kt + kc * 8, Bs + (wave * 2 + c) * 512);
        }
    };

    int wr = (wave >> 1) * 64, wc = (wave & 1) * 64;
    f32x4 acc[4][4] = {};
    stgB(0, Bs0); stgA(0, As0);
    for (int kt = 0; kt < 512; kt += 32) {
        short* Asc = (kt & 32) ? As1 : As0;
        short* Bsc = (kt & 32) ? Bs1 : Bs0;
        short* Asn = (kt & 32) ? As0 : As1;
        short* Bsn = (kt & 32) ? Bs0 : Bs1;
        __syncthreads();
        if (kt + 32 < 512) { stgB(kt + 32, Bsn); stgA(kt + 32, Asn); }
        bf16x8 af[4], bg[4];
        #pragma unroll
        for (int mf = 0; mf < 4; ++mf)
            af[mf] = *(const bf16x8*)(Asc + (wr + mf * 16 + cl) * 32 + (g << 3));
        #pragma unroll
        for (int nf = 0; nf < 4; ++nf)
            bg[nf] = *(const bf16x8*)(Bsc + (wc + nf * 16 + cl) * 32 + (g << 3));
        #pragma unroll
        for (int mf = 0; mf < 4; ++mf)
            #pragma unroll
            for (int nf = 0; nf < 4; ++nf)
                acc[mf][nf] = __builtin_amdgcn_mfma_f32_16x16x32_bf16(af[mf], bg[nf], acc[mf][nf], 0, 0, 0);
    }

    const float QSC = 0.125f * LOG2E;
    int gbase = bn * 128 + wc;        // 64-aligned absolute col base of this wave

    if (gbase < 640) {
        // q / k path (row-major outputs)
        #pragma unroll
        for (int mf = 0; mf < 4; ++mf) {
            #pragma unroll
            for (int rg = 0; rg < 4; ++rg) {
                int r = bm * 128 + wr + mf * 16 + (g << 2) + rg;
                int n = r >> 9, t = r & 511;
                #pragma unroll
                for (int nf = 0; nf < 2; ++nf) {
                    int dlo = nf * 16 + cl;              // [0,32)
                    float v1 = acc[mf][nf][rg];
                    float v2 = acc[mf][nf + 2][rg];
                    float c = cosT[t * 32 + dlo], s = sinT[t * 32 + dlo];
                    if (gbase < 512) {                   // q: rope + scale
                        int h = gbase >> 6;
                        size_t base = ((size_t)(n * 8 + h) * 512 + t) * 64;
                        qb[base + dlo]      = f2bf_hw((v1 * c - v2 * s) * QSC);
                        qb[base + dlo + 32] = f2bf_hw((v1 * s + v2 * c) * QSC);
                    } else {                             // k: rope
                        int gk = (gbase - 512) >> 6;
                        size_t base = ((size_t)(n * 2 + gk) * 512 + t) * 64;
                        kb[base + dlo]      = f2bf_hw(v1 * c - v2 * s);
                        kb[base + dlo + 32] = f2bf_hw(v1 * s + v2 * c);
                    }
                }
            }
        }
    } else {
        // v path: LDS transpose per mf (16 rows), then coalesced [d][t] stores
        int gq = (gbase - 640) >> 6;
        #pragma unroll
        for (int mf = 0; mf < 4; ++mf) {
            #pragma unroll
            for (int nf = 0; nf < 2; ++nf) {
                int dlo = nf * 16 + cl;
                s16x4 plo, phi;
                #pragma unroll
                for (int rg = 0; rg < 4; ++rg) {
                    ((short*)&plo)[rg] = f2bf_hw(acc[mf][nf][rg]);
                    ((short*)&phi)[rg] = f2bf_hw(acc[mf][nf + 2][rg]);
                }
                *(s16x4*)(&Vld[wave][dlo * 16 + (g << 2)])        = plo;
                *(s16x4*)(&Vld[wave][(dlo + 32) * 16 + (g << 2)]) = phi;
            }
            int r0 = bm * 128 + wr + mf * 16;       // 16-aligned -> single n,t0
            int n = r0 >> 9, t0 = r0 & 511;
            size_t vb = ((size_t)(n * 2 + gq) * 64 + lane) * 512;
            bf16x8 va = *(const bf16x8*)(&Vld[wave][lane * 16]);
            bf16x8 vb8 = *(const bf16x8*)(&Vld[wave][lane * 16 + 8]);
            *(bf16x8*)(vtb + vb + t0)     = va;
            *(bf16x8*)(vtb + vb + t0 + 8) = vb8;
        }
    }
}

// ---------------- kernel 2: causal GQA flash attention (two sequential phases) ----------------
// grid 1024 = n(32) x h(8) x c(4). Block processes q-chunk c (phase A, tiles 0..c) then
// q-chunk 7-c (phase B, tiles 0..7-c): 9 tiles for EVERY block (balanced); one unit's
// state live at a time. Diagonal (masked) tile is always the LAST tile of a phase.
// Swapped QK^T: lane owns q = rowb + (lane&15). Defer-max THR=8 (log2 domain).
// LDS 40960 B; K/V double-buffered via global_load_lds with source pre-swizzle.
__global__ __launch_bounds__(256) void k_attn(
    const short* __restrict__ qb, const short* __restrict__ kb, const short* __restrict__ vtb,
    const int* __restrict__ pm, short* __restrict__ ao)
{
    __shared__ short Kt[2][64 * 64];     // [kv][d], 16B chunks XOR-swizzled at the SOURCE
    __shared__ short Vt[2][64 * 64];     // [d][kv], same swizzle
    __shared__ short Pws[4][16 * 64];    // per-wave P[q=cl][kv], chunk-XOR swizzled
    int tid = threadIdx.x, wave = tid >> 6, lane = tid & 63;
    int cl = lane & 15, g = lane >> 4;
    int bid = blockIdx.x;
    int c = bid & 3, h = (bid >> 2) & 7, n = bid >> 5;
    int kg = h >> 2;
    const short* Qb = qb + ((size_t)(n * 8 + h) * 512) * 64;
    const short* Kb = kb + ((size_t)(n * 2 + kg) * 512) * 64;
    const short* Vb = vtb + ((size_t)(n * 2 + kg) * 64) * 512;

    auto stage = [&](int jt, int buf) {
        int c0 = jt * 64;
        #pragma unroll
        for (int cc = 0; cc < 2; ++cc) {
            int chunk = (wave * 2 + cc) * 64 + lane;
            int row = chunk >> 3, kc = chunk & 7;
            int sw = (kc ^ (row & 7)) << 3;
            gload16(Kb + (size_t)(c0 + row) * 64 + sw, &Kt[buf][(wave * 2 + cc) * 512]);
            gload16(Vb + (size_t)row * 512 + c0 + sw, &Vt[buf][(wave * 2 + cc) * 512]);
        }
    };

    stage(0, 0);
    int buf = 0;
    #pragma unroll
    for (int ph = 0; ph < 2; ++ph) {
        int rowb = (ph ? (7 - c) : c) * 64 + wave * 16;
        int NTp = ph ? (8 - c) : (c + 1);
        bf16x8 qf[2];
        #pragma unroll
        for (int ks = 0; ks < 2; ++ks)
            qf[ks] = *(const bf16x8*)(Qb + (size_t)(rowb + cl) * 64 + ks * 32 + (g << 3));
        f32x4 Oc[4] = {};
        float mrow = -1e30f, lrow = 0.f;
        bool rv = pm[n * 512 + rowb + cl] != 0;
        int rq = rowb + cl;                      // this lane's absolute q row

        for (int jt = 0; jt < NTp; ++jt) {
            __syncthreads();                     // drains vmcnt -> Kt/Vt[buf] ready
            if (jt + 1 < NTp) stage(jt + 1, buf ^ 1);
            else if (ph == 0) stage(0, buf ^ 1); // prefetch phase B's first tile
            int c0 = jt * 64;
            const short* Kc = Kt[buf];
            const short* Vc = Vt[buf];
            buf ^= 1;

            // S' = K Q (swapped): sacc[nf][rg] = S[kv = c0+nf*16+g*4+rg][q = rowb+cl]
            f32x4 sacc[4] = {};
            #pragma unroll
            for (int ks = 0; ks < 2; ++ks) {
                #pragma unroll
                for (int nf = 0; nf < 4; ++nf) {
                    int row = nf * 16 + cl;
                    int kc = ks * 4 + g;
                    bf16x8 kf = *(const bf16x8*)(Kc + row * 64 + ((kc ^ (row & 7)) << 3));
                    sacc[nf] = __builtin_amdgcn_mfma_f32_16x16x32_bf16(kf, qf[ks], sacc[nf], 0, 0, 0);
                }
            }

            // mask (diag tile only) + online softmax (per-lane q-row) + swizzled P store
            const bool diag = (jt == NTp - 1);
            float rmax = -1e30f;
            if (diag) {
                #pragma unroll
                for (int nf = 0; nf < 4; ++nf)
                    #pragma unroll
                    for (int rg = 0; rg < 4; ++rg) {
                        int kv = c0 + nf * 16 + g * 4 + rg;
                        float sv = sacc[nf][rg];
                        sv = (kv <= rq && rv) ? sv : NEG_INF_F;
                        sacc[nf][rg] = sv;
                        rmax = fmaxf(rmax, sv);
                    }
            } else {
                #pragma unroll
                for (int nf = 0; nf < 4; ++nf)
                    #pragma unroll
                    for (int rg = 0; rg < 4; ++rg)
                        rmax = fmaxf(rmax, sacc[nf][rg]);
            }
            rmax = fmaxf(rmax, __shfl_xor(rmax, 16));
            rmax = fmaxf(rmax, __shfl_xor(rmax, 32));
            float mold = mrow;
            int defer = __all(rmax - mold <= 8.0f);  // wave-uniform
            float mnew = defer ? mold : fmaxf(mold, rmax);
            mrow = mnew;
            float rsum = 0.f;
            #pragma unroll
            for (int nf = 0; nf < 4; ++nf) {
                s16x4 pk;
                #pragma unroll
                for (int rg = 0; rg < 4; ++rg) {
                    float p = exp2f(sacc[nf][rg] - mnew);
                    rsum += p;
                    ((short*)&pk)[rg] = f2bf_hw(p);
                }
                *(s16x4*)(&Pws[wave][cl * 64 + ((((nf << 1) + (g >> 1)) ^ (cl & 7)) << 3) + ((g & 1) << 2)]) = pk;
            }
            rsum += __shfl_xor(rsum, 16);
            rsum += __shfl_xor(rsum, 32);
            if (defer) {
                lrow += rsum;
            } else {
                float alpha = exp2f(mold - mnew);
                lrow = lrow * alpha + rsum;
                #pragma unroll
                for (int rg = 0; rg < 4; ++rg) {
                    float av = __shfl(alpha, (lane & 48) + (g << 2) + rg);
                    #pragma unroll
                    for (int nf = 0; nf < 4; ++nf) Oc[nf][rg] *= av;
                }
            }

            // O += P V   (A = P rows q, B = V^T rows d)
            #pragma unroll
            for (int ks = 0; ks < 2; ++ks) {
                bf16x8 pf = *(const bf16x8*)(&Pws[wave][cl * 64 + (((ks * 4 + g) ^ (cl & 7)) << 3)]);
                #pragma unroll
                for (int nf = 0; nf < 4; ++nf) {
                    int row = nf * 16 + cl;
                    int kc = ks * 4 + g;
                    bf16x8 vf = *(const bf16x8*)(Vc + row * 64 + ((kc ^ (row & 7)) << 3));
                    Oc[nf] = __builtin_amdgcn_mfma_f32_16x16x32_bf16(pf, vf, Oc[nf], 0, 0, 0);
                }
            }
        }

        // phase epilogue: O /= l (l redistributed to PV layout), write bf16
        #pragma unroll
        for (int rg = 0; rg < 4; ++rg) {
            float li = __shfl(lrow, (lane & 48) + (g << 2) + rg);
            float inv = 1.0f / li;
            int r = rowb + g * 4 + rg;
            size_t base = ((size_t)n * 512 + r) * 512 + h * 64;
            #pragma unroll
            for (int nf = 0; nf < 4; ++nf)
                ao[base + nf * 16 + cl] = f2bf_hw(Oc[nf][rg] * inv);
        }
    }
}

// ---------------- kernel 3: output projection + (B,T,S,D) scatter ----------------
__global__ __launch_bounds__(256) void k_gemm_out(
    const short* __restrict__ ao, const short* __restrict__ ow, float* __restrict__ out)
{
    __shared__ short As0[128 * 32], As1[128 * 32], Bs0[128 * 32], Bs1[128 * 32];
    int tid = threadIdx.x, wave = tid >> 6, lane = tid & 63;
    int bm = blockIdx.x, bn = blockIdx.y;
    f32x4 acc[4][4] = {};
    gemm_mainloop_db(ao + (size_t)bm * 128 * 512, ow + (size_t)bn * 128 * 512, 512,
                     As0, As1, Bs0, Bs1, wave, lane, acc);

    int wr = (wave >> 1) * 64, wc = (wave & 1) * 64;
    #pragma unroll
    for (int mf = 0; mf < 4; ++mf) {
        #pragma unroll
        for (int rg = 0; rg < 4; ++rg) {
            int r = bm * 128 + wr + mf * 16 + ((lane >> 4) << 2) + rg;
            int n = r >> 9, t = r & 511, b = n >> 4, s = n & 15;
            size_t obase = ((size_t)((b * 512 + t) * 16 + s)) * 512;
            #pragma unroll
            for (int nf = 0; nf < 4; ++nf) {
                int ccc = bn * 128 + wc + nf * 16 + (lane & 15);
                out[obase + ccc] = acc[mf][nf][rg];
            }
        }
    }
}

// ---------------- launch ----------------
extern "C" void kernel_launch(void* const* d_in, const int* in_sizes, int n_in,
                              void* d_out, int out_size, void* d_ws, size_t ws_size,
                              hipStream_t stream) {
    (void)in_sizes; (void)n_in; (void)out_size; (void)ws_size;
    const float* x    = (const float*)d_in[0];
    const int*   pmsk = (const int*)d_in[1];
    const float* qkvw = (const float*)d_in[2];
    const float* owf  = (const float*)d_in[3];
    char* ws = (char*)d_ws;
    short* aobuf= (short*)(ws + 0);          // 16,777,216 B (attn output)
    short* qw   = (short*)(ws + 16777216);   //    786,432 B
    short* ow   = (short*)(ws + 17563648);   //    524,288 B
    float* cosT = (float*)(ws + 18087936);   //     65,536 B
    float* sinT = (float*)(ws + 18153472);   //     65,536 B
    short* qbuf = (short*)(ws + 18219008);   // 16,777,216 B
    short* kbuf = (short*)(ws + 34996224);   //  4,194,304 B
    short* vtbuf= (short*)(ws + 39190528);   //  4,194,304 B  (end 43,384,832)
    float* out = (float*)d_out;

    k_convert<<<dim3(1408), dim3(128), 0, stream>>>(qkvw, owf, qw, ow, cosT, sinT);
    k_gemm_qkv<<<dim3(128, 6), dim3(256), 0, stream>>>(x, qw, cosT, sinT, qbuf, kbuf, vtbuf);
    k_attn<<<dim3(1024), dim3(256), 0, stream>>>(qbuf, kbuf, vtbuf, pmsk, aobuf);
    k_gemm_out<<<dim3(128, 4), dim3(256), 0, stream>>>(aobuf, ow, out);
}

// Round 10
// 98.788 us; speedup vs baseline: 1.0331x; 1.0331x over previous
//
#include <hip/hip_runtime.h>
#include <hip/hip_bf16.h>

// ---- types ----
typedef __attribute__((ext_vector_type(8))) short bf16x8;   // 8 bf16 in 4 VGPRs (MFMA A/B frag)
typedef __attribute__((ext_vector_type(4))) float f32x4;    // MFMA C/D frag
typedef __attribute__((ext_vector_type(4))) short s16x4;

#define DM 512
#define T_SEQ 512
#define NSEQ 32         // B*S = 2*16
#define MROWS 16384     // NSEQ * T_SEQ
#define QKV_DIM 768
#define HD 64
#define NEG_INF_F (-1000000000.0f)
#define LOG2E 1.44269504088896340736f

// f32 -> bf16 bits, round-to-nearest-even (software)
__device__ __forceinline__ short f2bf(float f) {
    unsigned int u = __builtin_bit_cast(unsigned int, f);
    unsigned int r = (u + 0x7FFFu + ((u >> 16) & 1u)) >> 16;
    return (short)r;
}

// HW convert (v_cvt path)
__device__ __forceinline__ short f2bf_hw(float f) {
    __hip_bfloat16 h = __float2bfloat16(f);
    return __builtin_bit_cast(short, h);
}

__device__ __forceinline__ void gload16(const void* g, void* l) {
    __builtin_amdgcn_global_load_lds(
        (const __attribute__((address_space(1))) void*)g,
        (__attribute__((address_space(3))) void*)l, 16, 0, 0);
}

// ---------------- kernel 0: weight converts + rope table ----------------
__global__ __launch_bounds__(128) void k_convert(
    const float* __restrict__ qkvw, const float* __restrict__ owf,
    short* __restrict__ qw, short* __restrict__ ow,
    float* __restrict__ cosT, float* __restrict__ sinT)
{
    int bidx = blockIdx.x, tid = threadIdx.x;
    if (bidx < 1280) {
        int wr = bidx;
        const float* src; short* dst;
        if (wr < QKV_DIM) { src = qkvw + (size_t)wr * 512; dst = qw + (size_t)wr * 512; }
        else             { src = owf + (size_t)(wr - QKV_DIM) * 512; dst = ow + (size_t)(wr - QKV_DIM) * 512; }
        float4 v = *(const float4*)(src + tid * 4);
        s16x4 o; o.x = f2bf(v.x); o.y = f2bf(v.y); o.z = f2bf(v.z); o.w = f2bf(v.w);
        *(s16x4*)(dst + tid * 4) = o;
    } else {
        int idx = (bidx - 1280) * 128 + tid;   // 0..16383 = t*32+d
        int t = idx >> 5, d = idx & 31;
        float inv = powf(10000.0f, -(float)d * (1.0f / 32.0f));
        float ang = (float)t * inv;
        float sv, cv; sincosf(ang, &sv, &cv);
        cosT[idx] = cv; sinT[idx] = sv;
    }
}

// ------- shared GEMM mainloop (bf16 A,B): 128x128 tile, BK=32, 4 waves, dbuf -------
__device__ __forceinline__ void gemm_mainloop_db(
    const short* __restrict__ Ab, const short* __restrict__ Bb, int K,
    short* As0, short* As1, short* Bs0, short* Bs1,
    int wave, int lane, f32x4 acc[4][4])
{
    int wr = (wave >> 1) * 64, wc = (wave & 1) * 64;
    int cl = lane & 15, g = lane >> 4;
    auto stg = [&](int kt, short* As, short* Bs) {
        #pragma unroll
        for (int c = 0; c < 2; ++c) {
            int chunk = (wave * 2 + c) * 64 + lane;
            int row = chunk >> 2, kc = chunk & 3;
            gload16(Ab + (size_t)row * K + kt + kc * 8, As + (wave * 2 + c) * 512);
            gload16(Bb + (size_t)row * K + kt + kc * 8, Bs + (wave * 2 + c) * 512);
        }
    };
    stg(0, As0, Bs0);
    for (int kt = 0; kt < K; kt += 32) {
        short* Asc = (kt & 32) ? As1 : As0;
        short* Bsc = (kt & 32) ? Bs1 : Bs0;
        short* Asn = (kt & 32) ? As0 : As1;
        short* Bsn = (kt & 32) ? Bs0 : Bs1;
        __syncthreads();                 // drains vmcnt -> current buf ready, prev reads done
        if (kt + 32 < K) stg(kt + 32, Asn, Bsn);
        bf16x8 af[4], bg[4];
        #pragma unroll
        for (int mf = 0; mf < 4; ++mf)
            af[mf] = *(const bf16x8*)(Asc + (wr + mf * 16 + cl) * 32 + (g << 3));
        #pragma unroll
        for (int nf = 0; nf < 4; ++nf)
            bg[nf] = *(const bf16x8*)(Bsc + (wc + nf * 16 + cl) * 32 + (g << 3));
        #pragma unroll
        for (int mf = 0; mf < 4; ++mf)
            #pragma unroll
            for (int nf = 0; nf < 4; ++nf)
                acc[mf][nf] = __builtin_amdgcn_mfma_f32_16x16x32_bf16(af[mf], bg[nf], acc[mf][nf], 0, 0, 0);
    }
}

// ---------------- kernel 1: QKV GEMM (A direct from f32 x) + RoPE epilogue ----------
// T14 async-STAGE split for A: loads for tile kt+64 ISSUED at end of iteration kt;
// cvt+ds_write for tile kt+32 done AFTER iteration kt's MFMAs (vmcnt wait lands
// post-MFMA with a full K-step of latency already elapsed). B via global_load_lds.
__global__ __launch_bounds__(256) void k_gemm_qkv(
    const float* __restrict__ x, const short* __restrict__ qw,
    const float* __restrict__ cosT, const float* __restrict__ sinT,
    short* __restrict__ qb, short* __restrict__ kb, short* __restrict__ vtb)
{
    __shared__ short As0[128 * 32], As1[128 * 32], Bs0[128 * 32], Bs1[128 * 32];
    __shared__ short Vld[4][16 * 64];   // per-wave transpose tile [d][t], 2KB each
    int tid = threadIdx.x, wave = tid >> 6, lane = tid & 63;
    int cl = lane & 15, g = lane >> 4;
    int bm = blockIdx.x, bn = blockIdx.y;
    const short* Bb = qw + (size_t)bn * 128 * 512;

    // prologue: per-chunk A row pointers (fixed across K)
    const float* xrowp[2];
    int choff[2];
    #pragma unroll
    for (int c = 0; c < 2; ++c) {
        int chunk = (wave * 2 + c) * 64 + lane;
        int row = chunk >> 2, kc = chunk & 3;
        int m = bm * 128 + row, n = m >> 9, t = m & 511, b = n >> 4, s = n & 15;
        xrowp[c] = x + ((size_t)((b * 512 + t) * 16 + s)) * 512 + kc * 8;
        choff[c] = chunk * 8;
    }
    auto stgB = [&](int kt, short* Bs) {
        #pragma unroll
        for (int c = 0; c < 2; ++c) {
            int chunk = (wave * 2 + c) * 64 + lane;
            int row = chunk >> 2, kc = chunk & 3;
            gload16(Bb + (size_t)row * 512 + kt + kc * 8, Bs + (wave * 2 + c) * 512);
        }
    };

    float4 ar[2][2];                       // in-flight A registers (issue-early)
    auto ldA = [&](int kt) {
        #pragma unroll
        for (int c = 0; c < 2; ++c) {
            ar[c][0] = *(const float4*)(xrowp[c] + kt);
            ar[c][1] = *(const float4*)(xrowp[c] + kt + 4);
        }
    };
    auto wrA = [&](short* As) {            // cvt + packed write (write-late)
        #pragma unroll
        for (int c = 0; c < 2; ++c) {
            bf16x8 v;
            v[0] = f2bf_hw(ar[c][0].x); v[1] = f2bf_hw(ar[c][0].y);
            v[2] = f2bf_hw(ar[c][0].z); v[3] = f2bf_hw(ar[c][0].w);
            v[4] = f2bf_hw(ar[c][1].x); v[5] = f2bf_hw(ar[c][1].y);
            v[6] = f2bf_hw(ar[c][1].z); v[7] = f2bf_hw(ar[c][1].w);
            *(bf16x8*)(As + choff[c]) = v;
        }
    };

    int wr = (wave >> 1) * 64, wc = (wave & 1) * 64;
    f32x4 acc[4][4] = {};
    stgB(0, Bs0);
    ldA(0); wrA(As0);                      // one-time exposed wait (prologue)
    ldA(32);                               // issue-early for kt=32
    for (int kt = 0; kt < 512; kt += 32) {
        short* Asc = (kt & 32) ? As1 : As0;
        short* Bsc = (kt & 32) ? Bs1 : Bs0;
        short* Asn = (kt & 32) ? As0 : As1;
        short* Bsn = (kt & 32) ? Bs0 : Bs1;
        __syncthreads();                   // current buffers ready
        if (kt + 32 < 512) stgB(kt + 32, Bsn);
        bf16x8 af[4], bg[4];
        #pragma unroll
        for (int mf = 0; mf < 4; ++mf)
            af[mf] = *(const bf16x8*)(Asc + (wr + mf * 16 + cl) * 32 + (g << 3));
        #pragma unroll
        for (int nf = 0; nf < 4; ++nf)
            bg[nf] = *(const bf16x8*)(Bsc + (wc + nf * 16 + cl) * 32 + (g << 3));
        #pragma unroll
        for (int mf = 0; mf < 4; ++mf)
            #pragma unroll
            for (int nf = 0; nf < 4; ++nf)
                acc[mf][nf] = __builtin_amdgcn_mfma_f32_16x16x32_bf16(af[mf], bg[nf], acc[mf][nf], 0, 0, 0);
        if (kt + 32 < 512) {
            wrA(Asn);                      // vmcnt wait lands here, post-MFMA
            if (kt + 64 < 512) ldA(kt + 64);
        }
    }

    const float QSC = 0.125f * LOG2E;
    int gbase = bn * 128 + wc;        // 64-aligned absolute col base of this wave

    if (gbase < 640) {
        // q / k path (row-major outputs)
        #pragma unroll
        for (int mf = 0; mf < 4; ++mf) {
            #pragma unroll
            for (int rg = 0; rg < 4; ++rg) {
                int r = bm * 128 + wr + mf * 16 + (g << 2) + rg;
                int n = r >> 9, t = r & 511;
                #pragma unroll
                for (int nf = 0; nf < 2; ++nf) {
                    int dlo = nf * 16 + cl;              // [0,32)
                    float v1 = acc[mf][nf][rg];
                    float v2 = acc[mf][nf + 2][rg];
                    float c = cosT[t * 32 + dlo], s = sinT[t * 32 + dlo];
                    if (gbase < 512) {                   // q: rope + scale
                        int h = gbase >> 6;
                        size_t base = ((size_t)(n * 8 + h) * 512 + t) * 64;
                        qb[base + dlo]      = f2bf_hw((v1 * c - v2 * s) * QSC);
                        qb[base + dlo + 32] = f2bf_hw((v1 * s + v2 * c) * QSC);
                    } else {                             // k: rope
                        int gk = (gbase - 512) >> 6;
                        size_t base = ((size_t)(n * 2 + gk) * 512 + t) * 64;
                        kb[base + dlo]      = f2bf_hw(v1 * c - v2 * s);
                        kb[base + dlo + 32] = f2bf_hw(v1 * s + v2 * c);
                    }
                }
            }
        }
    } else {
        // v path: LDS transpose per mf (16 rows), then coalesced [d][t] stores
        int gq = (gbase - 640) >> 6;
        #pragma unroll
        for (int mf = 0; mf < 4; ++mf) {
            #pragma unroll
            for (int nf = 0; nf < 2; ++nf) {
                int dlo = nf * 16 + cl;
                s16x4 plo, phi;
                #pragma unroll
                for (int rg = 0; rg < 4; ++rg) {
                    ((short*)&plo)[rg] = f2bf_hw(acc[mf][nf][rg]);
                    ((short*)&phi)[rg] = f2bf_hw(acc[mf][nf + 2][rg]);
                }
                *(s16x4*)(&Vld[wave][dlo * 16 + (g << 2)])        = plo;
                *(s16x4*)(&Vld[wave][(dlo + 32) * 16 + (g << 2)]) = phi;
            }
            int r0 = bm * 128 + wr + mf * 16;       // 16-aligned -> single n,t0
            int n = r0 >> 9, t0 = r0 & 511;
            size_t vb = ((size_t)(n * 2 + gq) * 64 + lane) * 512;
            bf16x8 va = *(const bf16x8*)(&Vld[wave][lane * 16]);
            bf16x8 vb8 = *(const bf16x8*)(&Vld[wave][lane * 16 + 8]);
            *(bf16x8*)(vtb + vb + t0)     = va;
            *(bf16x8*)(vtb + vb + t0 + 8) = vb8;
        }
    }
}

// ---------------- kernel 2: causal GQA flash attention (two sequential phases) ----------------
// grid 1024 = n(32) x h(8) x c(4). Block processes q-chunk c (phase A, tiles 0..c) then
// q-chunk 7-c (phase B, tiles 0..7-c): 9 tiles for EVERY block (balanced); one unit's
// state live at a time. Diagonal (masked) tile is always the LAST tile of a phase.
// Swapped QK^T: lane owns q = rowb + (lane&15). Defer-max THR=8 (log2 domain).
// LDS 40960 B; K/V double-buffered via global_load_lds with source pre-swizzle.
__global__ __launch_bounds__(256) void k_attn(
    const short* __restrict__ qb, const short* __restrict__ kb, const short* __restrict__ vtb,
    const int* __restrict__ pm, short* __restrict__ ao)
{
    __shared__ short Kt[2][64 * 64];     // [kv][d], 16B chunks XOR-swizzled at the SOURCE
    __shared__ short Vt[2][64 * 64];     // [d][kv], same swizzle
    __shared__ short Pws[4][16 * 64];    // per-wave P[q=cl][kv], chunk-XOR swizzled
    int tid = threadIdx.x, wave = tid >> 6, lane = tid & 63;
    int cl = lane & 15, g = lane >> 4;
    int bid = blockIdx.x;
    int c = bid & 3, h = (bid >> 2) & 7, n = bid >> 5;
    int kg = h >> 2;
    const short* Qb = qb + ((size_t)(n * 8 + h) * 512) * 64;
    const short* Kb = kb + ((size_t)(n * 2 + kg) * 512) * 64;
    const short* Vb = vtb + ((size_t)(n * 2 + kg) * 64) * 512;

    auto stage = [&](int jt, int buf) {
        int c0 = jt * 64;
        #pragma unroll
        for (int cc = 0; cc < 2; ++cc) {
            int chunk = (wave * 2 + cc) * 64 + lane;
            int row = chunk >> 3, kc = chunk & 7;
            int sw = (kc ^ (row & 7)) << 3;
            gload16(Kb + (size_t)(c0 + row) * 64 + sw, &Kt[buf][(wave * 2 + cc) * 512]);
            gload16(Vb + (size_t)row * 512 + c0 + sw, &Vt[buf][(wave * 2 + cc) * 512]);
        }
    };

    stage(0, 0);
    int buf = 0;
    #pragma unroll
    for (int ph = 0; ph < 2; ++ph) {
        int rowb = (ph ? (7 - c) : c) * 64 + wave * 16;
        int NTp = ph ? (8 - c) : (c + 1);
        bf16x8 qf[2];
        #pragma unroll
        for (int ks = 0; ks < 2; ++ks)
            qf[ks] = *(const bf16x8*)(Qb + (size_t)(rowb + cl) * 64 + ks * 32 + (g << 3));
        f32x4 Oc[4] = {};
        float mrow = -1e30f, lrow = 0.f;
        bool rv = pm[n * 512 + rowb + cl] != 0;
        int rq = rowb + cl;                      // this lane's absolute q row

        for (int jt = 0; jt < NTp; ++jt) {
            __syncthreads();                     // drains vmcnt -> Kt/Vt[buf] ready
            if (jt + 1 < NTp) stage(jt + 1, buf ^ 1);
            else if (ph == 0) stage(0, buf ^ 1); // prefetch phase B's first tile
            int c0 = jt * 64;
            const short* Kc = Kt[buf];
            const short* Vc = Vt[buf];
            buf ^= 1;

            // S' = K Q (swapped): sacc[nf][rg] = S[kv = c0+nf*16+g*4+rg][q = rowb+cl]
            f32x4 sacc[4] = {};
            #pragma unroll
            for (int ks = 0; ks < 2; ++ks) {
                #pragma unroll
                for (int nf = 0; nf < 4; ++nf) {
                    int row = nf * 16 + cl;
                    int kc = ks * 4 + g;
                    bf16x8 kf = *(const bf16x8*)(Kc + row * 64 + ((kc ^ (row & 7)) << 3));
                    sacc[nf] = __builtin_amdgcn_mfma_f32_16x16x32_bf16(kf, qf[ks], sacc[nf], 0, 0, 0);
                }
            }

            // mask (diag tile only) + online softmax (per-lane q-row) + swizzled P store
            const bool diag = (jt == NTp - 1);
            float rmax = -1e30f;
            if (diag) {
                #pragma unroll
                for (int nf = 0; nf < 4; ++nf)
                    #pragma unroll
                    for (int rg = 0; rg < 4; ++rg) {
                        int kv = c0 + nf * 16 + g * 4 + rg;
                        float sv = sacc[nf][rg];
                        sv = (kv <= rq && rv) ? sv : NEG_INF_F;
                        sacc[nf][rg] = sv;
                        rmax = fmaxf(rmax, sv);
                    }
            } else {
                #pragma unroll
                for (int nf = 0; nf < 4; ++nf)
                    #pragma unroll
                    for (int rg = 0; rg < 4; ++rg)
                        rmax = fmaxf(rmax, sacc[nf][rg]);
            }
            rmax = fmaxf(rmax, __shfl_xor(rmax, 16));
            rmax = fmaxf(rmax, __shfl_xor(rmax, 32));
            float mold = mrow;
            int defer = __all(rmax - mold <= 8.0f);  // wave-uniform
            float mnew = defer ? mold : fmaxf(mold, rmax);
            mrow = mnew;
            float rsum = 0.f;
            #pragma unroll
            for (int nf = 0; nf < 4; ++nf) {
                s16x4 pk;
                #pragma unroll
                for (int rg = 0; rg < 4; ++rg) {
                    float p = exp2f(sacc[nf][rg] - mnew);
                    rsum += p;
                    ((short*)&pk)[rg] = f2bf_hw(p);
                }
                *(s16x4*)(&Pws[wave][cl * 64 + ((((nf << 1) + (g >> 1)) ^ (cl & 7)) << 3) + ((g & 1) << 2)]) = pk;
            }
            rsum += __shfl_xor(rsum, 16);
            rsum += __shfl_xor(rsum, 32);
            if (defer) {
                lrow += rsum;
            } else {
                float alpha = exp2f(mold - mnew);
                lrow = lrow * alpha + rsum;
                #pragma unroll
                for (int rg = 0; rg < 4; ++rg) {
                    float av = __shfl(alpha, (lane & 48) + (g << 2) + rg);
                    #pragma unroll
                    for (int nf = 0; nf < 4; ++nf) Oc[nf][rg] *= av;
                }
            }

            // O += P V   (A = P rows q, B = V^T rows d)
            #pragma unroll
            for (int ks = 0; ks < 2; ++ks) {
                bf16x8 pf = *(const bf16x8*)(&Pws[wave][cl * 64 + (((ks * 4 + g) ^ (cl & 7)) << 3)]);
                #pragma unroll
                for (int nf = 0; nf < 4; ++nf) {
                    int row = nf * 16 + cl;
                    int kc = ks * 4 + g;
                    bf16x8 vf = *(const bf16x8*)(Vc + row * 64 + ((kc ^ (row & 7)) << 3));
                    Oc[nf] = __builtin_amdgcn_mfma_f32_16x16x32_bf16(pf, vf, Oc[nf], 0, 0, 0);
                }
            }
        }

        // phase epilogue: O /= l (l redistributed to PV layout), write bf16
        #pragma unroll
        for (int rg = 0; rg < 4; ++rg) {
            float li = __shfl(lrow, (lane & 48) + (g << 2) + rg);
            float inv = 1.0f / li;
            int r = rowb + g * 4 + rg;
            size_t base = ((size_t)n * 512 + r) * 512 + h * 64;
            #pragma unroll
            for (int nf = 0; nf < 4; ++nf)
                ao[base + nf * 16 + cl] = f2bf_hw(Oc[nf][rg] * inv);
        }
    }
}

// ---------------- kernel 3: output projection + (B,T,S,D) scatter ----------------
__global__ __launch_bounds__(256) void k_gemm_out(
    const short* __restrict__ ao, const short* __restrict__ ow, float* __restrict__ out)
{
    __shared__ short As0[128 * 32], As1[128 * 32], Bs0[128 * 32], Bs1[128 * 32];
    int tid = threadIdx.x, wave = tid >> 6, lane = tid & 63;
    int bm = blockIdx.x, bn = blockIdx.y;
    f32x4 acc[4][4] = {};
    gemm_mainloop_db(ao + (size_t)bm * 128 * 512, ow + (size_t)bn * 128 * 512, 512,
                     As0, As1, Bs0, Bs1, wave, lane, acc);

    int wr = (wave >> 1) * 64, wc = (wave & 1) * 64;
    #pragma unroll
    for (int mf = 0; mf < 4; ++mf) {
        #pragma unroll
        for (int rg = 0; rg < 4; ++rg) {
            int r = bm * 128 + wr + mf * 16 + ((lane >> 4) << 2) + rg;
            int n = r >> 9, t = r & 511, b = n >> 4, s = n & 15;
            size_t obase = ((size_t)((b * 512 + t) * 16 + s)) * 512;
            #pragma unroll
            for (int nf = 0; nf < 4; ++nf) {
                int ccc = bn * 128 + wc + nf * 16 + (lane & 15);
                out[obase + ccc] = acc[mf][nf][rg];
            }
        }
    }
}

// ---------------- launch ----------------
extern "C" void kernel_launch(void* const* d_in, const int* in_sizes, int n_in,
                              void* d_out, int out_size, void* d_ws, size_t ws_size,
                              hipStream_t stream) {
    (void)in_sizes; (void)n_in; (void)out_size; (void)ws_size;
    const float* x    = (const float*)d_in[0];
    const int*   pmsk = (const int*)d_in[1];
    const float* qkvw = (const float*)d_in[2];
    const float* owf  = (const float*)d_in[3];
    char* ws = (char*)d_ws;
    short* aobuf= (short*)(ws + 0);          // 16,777,216 B (attn output)
    short* qw   = (short*)(ws + 16777216);   //    786,432 B
    short* ow   = (short*)(ws + 17563648);   //    524,288 B
    float* cosT = (float*)(ws + 18087936);   //     65,536 B
    float* sinT = (float*)(ws + 18153472);   //     65,536 B
    short* qbuf = (short*)(ws + 18219008);   // 16,777,216 B
    short* kbuf = (short*)(ws + 34996224);   //  4,194,304 B
    short* vtbuf= (short*)(ws + 39190528);   //  4,194,304 B  (end 43,384,832)
    float* out = (float*)d_out;

    k_convert<<<dim3(1408), dim3(128), 0, stream>>>(qkvw, owf, qw, ow, cosT, sinT);
    k_gemm_qkv<<<dim3(128, 6), dim3(256), 0, stream>>>(x, qw, cosT, sinT, qbuf, kbuf, vtbuf);
    k_attn<<<dim3(1024), dim3(256), 0, stream>>>(qbuf, kbuf, vtbuf, pmsk, aobuf);
    k_gemm_out<<<dim3(128, 4), dim3(256), 0, stream>>>(aobuf, ow, out);
}

// Round 11
// 84.367 us; speedup vs baseline: 1.2097x; 1.1709x over previous
//
#include <hip/hip_runtime.h>
#include <hip/hip_bf16.h>

// ---- types ----
typedef __attribute__((ext_vector_type(8))) short bf16x8;   // 8 bf16 in 4 VGPRs (MFMA A/B frag)
typedef __attribute__((ext_vector_type(4))) float f32x4;    // MFMA C/D frag
typedef __attribute__((ext_vector_type(4))) short s16x4;

#define DM 512
#define T_SEQ 512
#define NSEQ 32         // B*S = 2*16
#define MROWS 16384     // NSEQ * T_SEQ
#define QKV_DIM 768
#define HD 64
#define NEG_INF_F (-1000000000.0f)
#define LOG2E 1.44269504088896340736f

// f32 -> bf16 bits, round-to-nearest-even (software)
__device__ __forceinline__ short f2bf(float f) {
    unsigned int u = __builtin_bit_cast(unsigned int, f);
    unsigned int r = (u + 0x7FFFu + ((u >> 16) & 1u)) >> 16;
    return (short)r;
}

// HW convert (v_cvt path)
__device__ __forceinline__ short f2bf_hw(float f) {
    __hip_bfloat16 h = __float2bfloat16(f);
    return __builtin_bit_cast(short, h);
}

__device__ __forceinline__ void gload16(const void* g, void* l) {
    __builtin_amdgcn_global_load_lds(
        (const __attribute__((address_space(1))) void*)g,
        (__attribute__((address_space(3))) void*)l, 16, 0, 0);
}

// ---------------- kernel 0: converts + rope table ----------------
__global__ __launch_bounds__(128) void k_convert(
    const float* __restrict__ x, const float* __restrict__ qkvw, const float* __restrict__ owf,
    short* __restrict__ xt, short* __restrict__ qw, short* __restrict__ ow,
    float* __restrict__ cosT, float* __restrict__ sinT)
{
    int bidx = blockIdx.x, tid = threadIdx.x;
    if (bidx < MROWS) {
        int m = bidx; int n = m >> 9, t = m & 511, b = n >> 4, s = n & 15;
        const float* src = x + ((size_t)((b * 512 + t) * 16 + s)) * 512;
        float4 v = *(const float4*)(src + tid * 4);
        s16x4 o; o.x = f2bf(v.x); o.y = f2bf(v.y); o.z = f2bf(v.z); o.w = f2bf(v.w);
        *(s16x4*)(xt + (size_t)m * 512 + tid * 4) = o;
    } else if (bidx < MROWS + 1280) {
        int wr = bidx - MROWS;
        const float* src; short* dst;
        if (wr < QKV_DIM) { src = qkvw + (size_t)wr * 512; dst = qw + (size_t)wr * 512; }
        else             { src = owf + (size_t)(wr - QKV_DIM) * 512; dst = ow + (size_t)(wr - QKV_DIM) * 512; }
        float4 v = *(const float4*)(src + tid * 4);
        s16x4 o; o.x = f2bf(v.x); o.y = f2bf(v.y); o.z = f2bf(v.z); o.w = f2bf(v.w);
        *(s16x4*)(dst + tid * 4) = o;
    } else {
        int idx = (bidx - (MROWS + 1280)) * 128 + tid;   // 0..16383 = t*32+d
        int t = idx >> 5, d = idx & 31;
        float inv = powf(10000.0f, -(float)d * (1.0f / 32.0f));
        float ang = (float)t * inv;
        float sv, cv; sincosf(ang, &sv, &cv);
        cosT[idx] = cv; sinT[idx] = sv;
    }
}

// ------- shared GEMM mainloop: 128x128 tile, BK=32, 4 waves, DOUBLE-BUFFERED -------
__device__ __forceinline__ void gemm_mainloop_db(
    const short* __restrict__ Ab, const short* __restrict__ Bb, int K,
    short* As0, short* As1, short* Bs0, short* Bs1,
    int wave, int lane, f32x4 acc[4][4])
{
    int wr = (wave >> 1) * 64, wc = (wave & 1) * 64;
    int cl = lane & 15, g = lane >> 4;
    auto stg = [&](int kt, short* As, short* Bs) {
        #pragma unroll
        for (int c = 0; c < 2; ++c) {
            int chunk = (wave * 2 + c) * 64 + lane;
            int row = chunk >> 2, kc = chunk & 3;
            gload16(Ab + (size_t)row * K + kt + kc * 8, As + (wave * 2 + c) * 512);
            gload16(Bb + (size_t)row * K + kt + kc * 8, Bs + (wave * 2 + c) * 512);
        }
    };
    stg(0, As0, Bs0);
    for (int kt = 0; kt < K; kt += 32) {
        short* Asc = (kt & 32) ? As1 : As0;
        short* Bsc = (kt & 32) ? Bs1 : Bs0;
        short* Asn = (kt & 32) ? As0 : As1;
        short* Bsn = (kt & 32) ? Bs0 : Bs1;
        __syncthreads();                 // drains vmcnt -> current buf ready, prev reads done
        if (kt + 32 < K) stg(kt + 32, Asn, Bsn);
        bf16x8 af[4], bg[4];
        #pragma unroll
        for (int mf = 0; mf < 4; ++mf)
            af[mf] = *(const bf16x8*)(Asc + (wr + mf * 16 + cl) * 32 + (g << 3));
        #pragma unroll
        for (int nf = 0; nf < 4; ++nf)
            bg[nf] = *(const bf16x8*)(Bsc + (wc + nf * 16 + cl) * 32 + (g << 3));
        #pragma unroll
        for (int mf = 0; mf < 4; ++mf)
            #pragma unroll
            for (int nf = 0; nf < 4; ++nf)
                acc[mf][nf] = __builtin_amdgcn_mfma_f32_16x16x32_bf16(af[mf], bg[nf], acc[mf][nf], 0, 0, 0);
    }
}

// ---------------- kernel 1: QKV GEMM + fused RoPE epilogue ----------------
// Q pre-scaled by 0.125*log2(e). V written TRANSPOSED vtb[n,g][d][t] via per-wave
// LDS transpose tile (packed b64 writes, 16B coalesced global stores).
__global__ __launch_bounds__(256) void k_gemm_qkv(
    const short* __restrict__ xt, const short* __restrict__ qw,
    const float* __restrict__ cosT, const float* __restrict__ sinT,
    short* __restrict__ qb, short* __restrict__ kb, short* __restrict__ vtb)
{
    __shared__ short As0[128 * 32], As1[128 * 32], Bs0[128 * 32], Bs1[128 * 32];
    __shared__ short Vld[4][16 * 64];   // per-wave transpose tile [d][t], 2KB each
    int tid = threadIdx.x, wave = tid >> 6, lane = tid & 63;
    int cl = lane & 15, g = lane >> 4;
    int bm = blockIdx.x, bn = blockIdx.y;
    f32x4 acc[4][4] = {};
    gemm_mainloop_db(xt + (size_t)bm * 128 * 512, qw + (size_t)bn * 128 * 512, 512,
                     As0, As1, Bs0, Bs1, wave, lane, acc);

    const float QSC = 0.125f * LOG2E;
    int wr = (wave >> 1) * 64, wc = (wave & 1) * 64;
    int gbase = bn * 128 + wc;        // 64-aligned absolute col base of this wave

    if (gbase < 640) {
        // q / k path (row-major outputs, 32B-coalesced quarter-wave groups)
        #pragma unroll
        for (int mf = 0; mf < 4; ++mf) {
            #pragma unroll
            for (int rg = 0; rg < 4; ++rg) {
                int r = bm * 128 + wr + mf * 16 + (g << 2) + rg;
                int n = r >> 9, t = r & 511;
                #pragma unroll
                for (int nf = 0; nf < 2; ++nf) {
                    int dlo = nf * 16 + cl;              // [0,32)
                    float v1 = acc[mf][nf][rg];
                    float v2 = acc[mf][nf + 2][rg];
                    float c = cosT[t * 32 + dlo], s = sinT[t * 32 + dlo];
                    if (gbase < 512) {                   // q: rope + scale
                        int h = gbase >> 6;
                        size_t base = ((size_t)(n * 8 + h) * 512 + t) * 64;
                        qb[base + dlo]      = f2bf_hw((v1 * c - v2 * s) * QSC);
                        qb[base + dlo + 32] = f2bf_hw((v1 * s + v2 * c) * QSC);
                    } else {                             // k: rope
                        int gk = (gbase - 512) >> 6;
                        size_t base = ((size_t)(n * 2 + gk) * 512 + t) * 64;
                        kb[base + dlo]      = f2bf_hw(v1 * c - v2 * s);
                        kb[base + dlo + 32] = f2bf_hw(v1 * s + v2 * c);
                    }
                }
            }
        }
    } else {
        // v path: LDS transpose per mf (16 rows), then coalesced [d][t] stores
        int gq = (gbase - 640) >> 6;
        #pragma unroll
        for (int mf = 0; mf < 4; ++mf) {
            #pragma unroll
            for (int nf = 0; nf < 2; ++nf) {
                int dlo = nf * 16 + cl;
                s16x4 plo, phi;
                #pragma unroll
                for (int rg = 0; rg < 4; ++rg) {
                    ((short*)&plo)[rg] = f2bf_hw(acc[mf][nf][rg]);
                    ((short*)&phi)[rg] = f2bf_hw(acc[mf][nf + 2][rg]);
                }
                // t-quad (g*4..g*4+3) contiguous -> packed b64 writes
                *(s16x4*)(&Vld[wave][dlo * 16 + (g << 2)])        = plo;
                *(s16x4*)(&Vld[wave][(dlo + 32) * 16 + (g << 2)]) = phi;
            }
            // wave-private tile: same-wave LDS ordering, no barrier needed
            int r0 = bm * 128 + wr + mf * 16;       // 16-aligned -> single n,t0
            int n = r0 >> 9, t0 = r0 & 511;
            size_t vb = ((size_t)(n * 2 + gq) * 64 + lane) * 512;
            bf16x8 va = *(const bf16x8*)(&Vld[wave][lane * 16]);
            bf16x8 vb8 = *(const bf16x8*)(&Vld[wave][lane * 16 + 8]);
            *(bf16x8*)(vtb + vb + t0)     = va;
            *(bf16x8*)(vtb + vb + t0 + 8) = vb8;
        }
    }
}

// ---------------- kernel 2: causal GQA flash attention (two sequential phases) ----------------
// grid 1024 = n(32) x h(8) x c(4). Block processes q-chunk c (phase A, tiles 0..c) then
// q-chunk 7-c (phase B, tiles 0..7-c): 9 tiles for EVERY block (balanced); one unit's
// state live at a time. Diagonal (masked) tile is always the LAST tile of a phase.
// Swapped QK^T: lane owns q = rowb + (lane&15). Defer-max THR=8 (log2 domain).
// LDS 40960 B; K/V double-buffered via global_load_lds with source pre-swizzle.
__global__ __launch_bounds__(256) void k_attn(
    const short* __restrict__ qb, const short* __restrict__ kb, const short* __restrict__ vtb,
    const int* __restrict__ pm, short* __restrict__ ao)
{
    __shared__ short Kt[2][64 * 64];     // [kv][d], 16B chunks XOR-swizzled at the SOURCE
    __shared__ short Vt[2][64 * 64];     // [d][kv], same swizzle
    __shared__ short Pws[4][16 * 64];    // per-wave P[q=cl][kv], chunk-XOR swizzled
    int tid = threadIdx.x, wave = tid >> 6, lane = tid & 63;
    int cl = lane & 15, g = lane >> 4;
    int bid = blockIdx.x;
    int c = bid & 3, h = (bid >> 2) & 7, n = bid >> 5;
    int kg = h >> 2;
    const short* Qb = qb + ((size_t)(n * 8 + h) * 512) * 64;
    const short* Kb = kb + ((size_t)(n * 2 + kg) * 512) * 64;
    const short* Vb = vtb + ((size_t)(n * 2 + kg) * 64) * 512;

    auto stage = [&](int jt, int buf) {
        int c0 = jt * 64;
        #pragma unroll
        for (int cc = 0; cc < 2; ++cc) {
            int chunk = (wave * 2 + cc) * 64 + lane;
            int row = chunk >> 3, kc = chunk & 7;
            int sw = (kc ^ (row & 7)) << 3;
            gload16(Kb + (size_t)(c0 + row) * 64 + sw, &Kt[buf][(wave * 2 + cc) * 512]);
            gload16(Vb + (size_t)row * 512 + c0 + sw, &Vt[buf][(wave * 2 + cc) * 512]);
        }
    };

    stage(0, 0);
    int buf = 0;
    #pragma unroll
    for (int ph = 0; ph < 2; ++ph) {
        int rowb = (ph ? (7 - c) : c) * 64 + wave * 16;
        int NTp = ph ? (8 - c) : (c + 1);
        bf16x8 qf[2];
        #pragma unroll
        for (int ks = 0; ks < 2; ++ks)
            qf[ks] = *(const bf16x8*)(Qb + (size_t)(rowb + cl) * 64 + ks * 32 + (g << 3));
        f32x4 Oc[4] = {};
        float mrow = -1e30f, lrow = 0.f;
        bool rv = pm[n * 512 + rowb + cl] != 0;
        int rq = rowb + cl;                      // this lane's absolute q row

        for (int jt = 0; jt < NTp; ++jt) {
            __syncthreads();                     // drains vmcnt -> Kt/Vt[buf] ready
            if (jt + 1 < NTp) stage(jt + 1, buf ^ 1);
            else if (ph == 0) stage(0, buf ^ 1); // prefetch phase B's first tile
            int c0 = jt * 64;
            const short* Kc = Kt[buf];
            const short* Vc = Vt[buf];
            buf ^= 1;

            // S' = K Q (swapped): sacc[nf][rg] = S[kv = c0+nf*16+g*4+rg][q = rowb+cl]
            f32x4 sacc[4] = {};
            #pragma unroll
            for (int ks = 0; ks < 2; ++ks) {
                #pragma unroll
                for (int nf = 0; nf < 4; ++nf) {
                    int row = nf * 16 + cl;
                    int kc = ks * 4 + g;
                    bf16x8 kf = *(const bf16x8*)(Kc + row * 64 + ((kc ^ (row & 7)) << 3));
                    sacc[nf] = __builtin_amdgcn_mfma_f32_16x16x32_bf16(kf, qf[ks], sacc[nf], 0, 0, 0);
                }
            }

            // mask (diag tile only) + online softmax (per-lane q-row) + swizzled P store
            const bool diag = (jt == NTp - 1);
            float rmax = -1e30f;
            if (diag) {
                #pragma unroll
                for (int nf = 0; nf < 4; ++nf)
                    #pragma unroll
                    for (int rg = 0; rg < 4; ++rg) {
                        int kv = c0 + nf * 16 + g * 4 + rg;
                        float sv = sacc[nf][rg];
                        sv = (kv <= rq && rv) ? sv : NEG_INF_F;
                        sacc[nf][rg] = sv;
                        rmax = fmaxf(rmax, sv);
                    }
            } else {
                #pragma unroll
                for (int nf = 0; nf < 4; ++nf)
                    #pragma unroll
                    for (int rg = 0; rg < 4; ++rg)
                        rmax = fmaxf(rmax, sacc[nf][rg]);
            }
            rmax = fmaxf(rmax, __shfl_xor(rmax, 16));
            rmax = fmaxf(rmax, __shfl_xor(rmax, 32));
            float mold = mrow;
            int defer = __all(rmax - mold <= 8.0f);  // wave-uniform
            float mnew = defer ? mold : fmaxf(mold, rmax);
            mrow = mnew;
            float rsum = 0.f;
            #pragma unroll
            for (int nf = 0; nf < 4; ++nf) {
                s16x4 pk;
                #pragma unroll
                for (int rg = 0; rg < 4; ++rg) {
                    float p = exp2f(sacc[nf][rg] - mnew);
                    rsum += p;
                    ((short*)&pk)[rg] = f2bf_hw(p);
                }
                *(s16x4*)(&Pws[wave][cl * 64 + ((((nf << 1) + (g >> 1)) ^ (cl & 7)) << 3) + ((g & 1) << 2)]) = pk;
            }
            rsum += __shfl_xor(rsum, 16);
            rsum += __shfl_xor(rsum, 32);
            if (defer) {
                lrow += rsum;
            } else {
                float alpha = exp2f(mold - mnew);
                lrow = lrow * alpha + rsum;
                #pragma unroll
                for (int rg = 0; rg < 4; ++rg) {
                    float av = __shfl(alpha, (lane & 48) + (g << 2) + rg);
                    #pragma unroll
                    for (int nf = 0; nf < 4; ++nf) Oc[nf][rg] *= av;
                }
            }

            // O += P V   (A = P rows q, B = V^T rows d)
            #pragma unroll
            for (int ks = 0; ks < 2; ++ks) {
                bf16x8 pf = *(const bf16x8*)(&Pws[wave][cl * 64 + (((ks * 4 + g) ^ (cl & 7)) << 3)]);
                #pragma unroll
                for (int nf = 0; nf < 4; ++nf) {
                    int row = nf * 16 + cl;
                    int kc = ks * 4 + g;
                    bf16x8 vf = *(const bf16x8*)(Vc + row * 64 + ((kc ^ (row & 7)) << 3));
                    Oc[nf] = __builtin_amdgcn_mfma_f32_16x16x32_bf16(pf, vf, Oc[nf], 0, 0, 0);
                }
            }
        }

        // phase epilogue: O /= l (l redistributed to PV layout), write bf16
        #pragma unroll
        for (int rg = 0; rg < 4; ++rg) {
            float li = __shfl(lrow, (lane & 48) + (g << 2) + rg);
            float inv = 1.0f / li;
            int r = rowb + g * 4 + rg;
            size_t base = ((size_t)n * 512 + r) * 512 + h * 64;
            #pragma unroll
            for (int nf = 0; nf < 4; ++nf)
                ao[base + nf * 16 + cl] = f2bf_hw(Oc[nf][rg] * inv);
        }
    }
}

// ---------------- kernel 3: output projection + (B,T,S,D) scatter ----------------
__global__ __launch_bounds__(256) void k_gemm_out(
    const short* __restrict__ ao, const short* __restrict__ ow, float* __restrict__ out)
{
    __shared__ short As0[128 * 32], As1[128 * 32], Bs0[128 * 32], Bs1[128 * 32];
    int tid = threadIdx.x, wave = tid >> 6, lane = tid & 63;
    int bm = blockIdx.x, bn = blockIdx.y;
    f32x4 acc[4][4] = {};
    gemm_mainloop_db(ao + (size_t)bm * 128 * 512, ow + (size_t)bn * 128 * 512, 512,
                     As0, As1, Bs0, Bs1, wave, lane, acc);

    int wr = (wave >> 1) * 64, wc = (wave & 1) * 64;
    #pragma unroll
    for (int mf = 0; mf < 4; ++mf) {
        #pragma unroll
        for (int rg = 0; rg < 4; ++rg) {
            int r = bm * 128 + wr + mf * 16 + ((lane >> 4) << 2) + rg;
            int n = r >> 9, t = r & 511, b = n >> 4, s = n & 15;
            size_t obase = ((size_t)((b * 512 + t) * 16 + s)) * 512;
            #pragma unroll
            for (int nf = 0; nf < 4; ++nf) {
                int ccc = bn * 128 + wc + nf * 16 + (lane & 15);
                out[obase + ccc] = acc[mf][nf][rg];
            }
        }
    }
}

// ---------------- launch ----------------
extern "C" void kernel_launch(void* const* d_in, const int* in_sizes, int n_in,
                              void* d_out, int out_size, void* d_ws, size_t ws_size,
                              hipStream_t stream) {
    (void)in_sizes; (void)n_in; (void)out_size; (void)ws_size;
    const float* x    = (const float*)d_in[0];
    const int*   pmsk = (const int*)d_in[1];
    const float* qkvw = (const float*)d_in[2];
    const float* owf  = (const float*)d_in[3];
    char* ws = (char*)d_ws;
    short* xt   = (short*)(ws + 0);          // 16,777,216 B (reused as attn-out)
    short* qw   = (short*)(ws + 16777216);   //    786,432 B
    short* ow   = (short*)(ws + 17563648);   //    524,288 B
    float* cosT = (float*)(ws + 18087936);   //     65,536 B
    float* sinT = (float*)(ws + 18153472);   //     65,536 B
    short* qbuf = (short*)(ws + 18219008);   // 16,777,216 B
    short* kbuf = (short*)(ws + 34996224);   //  4,194,304 B
    short* vtbuf= (short*)(ws + 39190528);   //  4,194,304 B  (end 43,384,832)
    short* aobuf = xt;                       // xt dead after GEMM1 -> reuse
    float* out = (float*)d_out;

    k_convert<<<dim3(17792), dim3(128), 0, stream>>>(x, qkvw, owf, xt, qw, ow, cosT, sinT);
    k_gemm_qkv<<<dim3(128, 6), dim3(256), 0, stream>>>(xt, qw, cosT, sinT, qbuf, kbuf, vtbuf);
    k_attn<<<dim3(1024), dim3(256), 0, stream>>>(qbuf, kbuf, vtbuf, pmsk, aobuf);
    k_gemm_out<<<dim3(128, 4), dim3(256), 0, stream>>>(aobuf, ow, out);
}

// Round 12
// 78.700 us; speedup vs baseline: 1.2968x; 1.0720x over previous
//
#include <hip/hip_runtime.h>
#include <hip/hip_bf16.h>

// ---- types ----
typedef __attribute__((ext_vector_type(8))) short bf16x8;   // 8 bf16 in 4 VGPRs (MFMA A/B frag)
typedef __attribute__((ext_vector_type(4))) float f32x4;    // MFMA C/D frag
typedef __attribute__((ext_vector_type(4))) short s16x4;

#define DM 512
#define T_SEQ 512
#define NSEQ 32         // B*S = 2*16
#define MROWS 16384     // NSEQ * T_SEQ
#define QKV_DIM 768
#define HD 64
#define NEG_INF_F (-1000000000.0f)
#define LOG2E 1.44269504088896340736f

// f32 -> bf16 bits, round-to-nearest-even (software)
__device__ __forceinline__ short f2bf(float f) {
    unsigned int u = __builtin_bit_cast(unsigned int, f);
    unsigned int r = (u + 0x7FFFu + ((u >> 16) & 1u)) >> 16;
    return (short)r;
}

// HW convert (v_cvt path)
__device__ __forceinline__ short f2bf_hw(float f) {
    __hip_bfloat16 h = __float2bfloat16(f);
    return __builtin_bit_cast(short, h);
}

__device__ __forceinline__ void gload16(const void* g, void* l) {
    __builtin_amdgcn_global_load_lds(
        (const __attribute__((address_space(1))) void*)g,
        (__attribute__((address_space(3))) void*)l, 16, 0, 0);
}

// ---------------- kernel 0: converts + rope table ----------------
__global__ __launch_bounds__(128) void k_convert(
    const float* __restrict__ x, const float* __restrict__ qkvw, const float* __restrict__ owf,
    short* __restrict__ xt, short* __restrict__ qw, short* __restrict__ ow,
    float* __restrict__ cosT, float* __restrict__ sinT)
{
    int bidx = blockIdx.x, tid = threadIdx.x;
    if (bidx < MROWS) {
        int m = bidx; int n = m >> 9, t = m & 511, b = n >> 4, s = n & 15;
        const float* src = x + ((size_t)((b * 512 + t) * 16 + s)) * 512;
        float4 v = *(const float4*)(src + tid * 4);
        s16x4 o; o.x = f2bf(v.x); o.y = f2bf(v.y); o.z = f2bf(v.z); o.w = f2bf(v.w);
        *(s16x4*)(xt + (size_t)m * 512 + tid * 4) = o;
    } else if (bidx < MROWS + 1280) {
        int wr = bidx - MROWS;
        const float* src; short* dst;
        if (wr < QKV_DIM) { src = qkvw + (size_t)wr * 512; dst = qw + (size_t)wr * 512; }
        else             { src = owf + (size_t)(wr - QKV_DIM) * 512; dst = ow + (size_t)(wr - QKV_DIM) * 512; }
        float4 v = *(const float4*)(src + tid * 4);
        s16x4 o; o.x = f2bf(v.x); o.y = f2bf(v.y); o.z = f2bf(v.z); o.w = f2bf(v.w);
        *(s16x4*)(dst + tid * 4) = o;
    } else {
        int idx = (bidx - (MROWS + 1280)) * 128 + tid;   // 0..16383 = t*32+d
        int t = idx >> 5, d = idx & 31;
        float inv = powf(10000.0f, -(float)d * (1.0f / 32.0f));
        float ang = (float)t * inv;
        float sv, cv; sincosf(ang, &sv, &cv);
        cosT[idx] = cv; sinT[idx] = sv;
    }
}

// ------- shared GEMM mainloop: 128x128 tile, BK=32, 4 waves, DOUBLE-BUFFERED -------
__device__ __forceinline__ void gemm_mainloop_db(
    const short* __restrict__ Ab, const short* __restrict__ Bb, int K,
    short* As0, short* As1, short* Bs0, short* Bs1,
    int wave, int lane, f32x4 acc[4][4])
{
    int wr = (wave >> 1) * 64, wc = (wave & 1) * 64;
    int cl = lane & 15, g = lane >> 4;
    auto stg = [&](int kt, short* As, short* Bs) {
        #pragma unroll
        for (int c = 0; c < 2; ++c) {
            int chunk = (wave * 2 + c) * 64 + lane;
            int row = chunk >> 2, kc = chunk & 3;
            gload16(Ab + (size_t)row * K + kt + kc * 8, As + (wave * 2 + c) * 512);
            gload16(Bb + (size_t)row * K + kt + kc * 8, Bs + (wave * 2 + c) * 512);
        }
    };
    stg(0, As0, Bs0);
    for (int kt = 0; kt < K; kt += 32) {
        short* Asc = (kt & 32) ? As1 : As0;
        short* Bsc = (kt & 32) ? Bs1 : Bs0;
        short* Asn = (kt & 32) ? As0 : As1;
        short* Bsn = (kt & 32) ? Bs0 : Bs1;
        __syncthreads();                 // drains vmcnt -> current buf ready, prev reads done
        if (kt + 32 < K) stg(kt + 32, Asn, Bsn);
        bf16x8 af[4], bg[4];
        #pragma unroll
        for (int mf = 0; mf < 4; ++mf)
            af[mf] = *(const bf16x8*)(Asc + (wr + mf * 16 + cl) * 32 + (g << 3));
        #pragma unroll
        for (int nf = 0; nf < 4; ++nf)
            bg[nf] = *(const bf16x8*)(Bsc + (wc + nf * 16 + cl) * 32 + (g << 3));
        #pragma unroll
        for (int mf = 0; mf < 4; ++mf)
            #pragma unroll
            for (int nf = 0; nf < 4; ++nf)
                acc[mf][nf] = __builtin_amdgcn_mfma_f32_16x16x32_bf16(af[mf], bg[nf], acc[mf][nf], 0, 0, 0);
    }
}

// ---------------- kernel 1: QKV GEMM + fused RoPE epilogue ----------------
// Q pre-scaled by 0.125*log2(e). V written TRANSPOSED vtb[n,g][d][t] via per-wave
// LDS transpose tile (packed b64 writes, 16B coalesced global stores).
__global__ __launch_bounds__(256) void k_gemm_qkv(
    const short* __restrict__ xt, const short* __restrict__ qw,
    const float* __restrict__ cosT, const float* __restrict__ sinT,
    short* __restrict__ qb, short* __restrict__ kb, short* __restrict__ vtb)
{
    __shared__ short As0[128 * 32], As1[128 * 32], Bs0[128 * 32], Bs1[128 * 32];
    __shared__ short Vld[4][16 * 64];   // per-wave transpose tile [d][t], 2KB each
    int tid = threadIdx.x, wave = tid >> 6, lane = tid & 63;
    int cl = lane & 15, g = lane >> 4;
    int bm = blockIdx.x, bn = blockIdx.y;
    f32x4 acc[4][4] = {};
    gemm_mainloop_db(xt + (size_t)bm * 128 * 512, qw + (size_t)bn * 128 * 512, 512,
                     As0, As1, Bs0, Bs1, wave, lane, acc);

    const float QSC = 0.125f * LOG2E;
    int wr = (wave >> 1) * 64, wc = (wave & 1) * 64;
    int gbase = bn * 128 + wc;        // 64-aligned absolute col base of this wave

    if (gbase < 640) {
        // q / k path (row-major outputs, 32B-coalesced quarter-wave groups)
        #pragma unroll
        for (int mf = 0; mf < 4; ++mf) {
            #pragma unroll
            for (int rg = 0; rg < 4; ++rg) {
                int r = bm * 128 + wr + mf * 16 + (g << 2) + rg;
                int n = r >> 9, t = r & 511;
                #pragma unroll
                for (int nf = 0; nf < 2; ++nf) {
                    int dlo = nf * 16 + cl;              // [0,32)
                    float v1 = acc[mf][nf][rg];
                    float v2 = acc[mf][nf + 2][rg];
                    float c = cosT[t * 32 + dlo], s = sinT[t * 32 + dlo];
                    if (gbase < 512) {                   // q: rope + scale
                        int h = gbase >> 6;
                        size_t base = ((size_t)(n * 8 + h) * 512 + t) * 64;
                        qb[base + dlo]      = f2bf_hw((v1 * c - v2 * s) * QSC);
                        qb[base + dlo + 32] = f2bf_hw((v1 * s + v2 * c) * QSC);
                    } else {                             // k: rope
                        int gk = (gbase - 512) >> 6;
                        size_t base = ((size_t)(n * 2 + gk) * 512 + t) * 64;
                        kb[base + dlo]      = f2bf_hw(v1 * c - v2 * s);
                        kb[base + dlo + 32] = f2bf_hw(v1 * s + v2 * c);
                    }
                }
            }
        }
    } else {
        // v path: LDS transpose per mf (16 rows), then coalesced [d][t] stores
        int gq = (gbase - 640) >> 6;
        #pragma unroll
        for (int mf = 0; mf < 4; ++mf) {
            #pragma unroll
            for (int nf = 0; nf < 2; ++nf) {
                int dlo = nf * 16 + cl;
                s16x4 plo, phi;
                #pragma unroll
                for (int rg = 0; rg < 4; ++rg) {
                    ((short*)&plo)[rg] = f2bf_hw(acc[mf][nf][rg]);
                    ((short*)&phi)[rg] = f2bf_hw(acc[mf][nf + 2][rg]);
                }
                // t-quad (g*4..g*4+3) contiguous -> packed b64 writes
                *(s16x4*)(&Vld[wave][dlo * 16 + (g << 2)])        = plo;
                *(s16x4*)(&Vld[wave][(dlo + 32) * 16 + (g << 2)]) = phi;
            }
            // wave-private tile: same-wave LDS ordering, no barrier needed
            int r0 = bm * 128 + wr + mf * 16;       // 16-aligned -> single n,t0
            int n = r0 >> 9, t0 = r0 & 511;
            size_t vb = ((size_t)(n * 2 + gq) * 64 + lane) * 512;
            bf16x8 va = *(const bf16x8*)(&Vld[wave][lane * 16]);
            bf16x8 vb8 = *(const bf16x8*)(&Vld[wave][lane * 16 + 8]);
            *(bf16x8*)(vtb + vb + t0)     = va;
            *(bf16x8*)(vtb + vb + t0 + 8) = vb8;
        }
    }
}

// ---------------- kernel 2: causal GQA flash attention (2 heads/block, 8 waves) --------
// grid 512 = n(32) x hp(4) x c(4), 512 threads. Waves 0-3 -> head hp*2 (row-quarter u),
// waves 4-7 -> head hp*2+1. Both heads share kg -> ONE K/V staging serves 8 waves
// (per-tile staging per wave: 1 K + 1 V gload16, was 2+2 for 4 waves).
// Per-wave logic identical to R11: two sequential phases (chunk c then 7-c, 9 tiles
// total, balanced), swapped QK^T (lane owns q = rowb + (lane&15)), diag-only mask,
// defer-max THR=8 (log2 domain), per-wave swizzled P through LDS.
__global__ __launch_bounds__(512) void k_attn(
    const short* __restrict__ qb, const short* __restrict__ kb, const short* __restrict__ vtb,
    const int* __restrict__ pm, short* __restrict__ ao)
{
    __shared__ short Kt[2][64 * 64];     // [kv][d], 16B chunks XOR-swizzled at the SOURCE
    __shared__ short Vt[2][64 * 64];     // [d][kv], same swizzle
    __shared__ short Pws[8][16 * 64];    // per-wave P[q=cl][kv], chunk-XOR swizzled
    int tid = threadIdx.x, wave = tid >> 6, lane = tid & 63;
    int cl = lane & 15, g = lane >> 4;
    int bid = blockIdx.x;
    int c = bid & 3, hp = (bid >> 2) & 3, n = bid >> 4;
    int kg = hp >> 1;
    int h = hp * 2 + (wave >> 2);        // per-wave head
    int u = wave & 3;                    // row-quarter within chunk
    const short* Qb = qb + ((size_t)(n * 8 + h) * 512) * 64;
    const short* Kb = kb + ((size_t)(n * 2 + kg) * 512) * 64;
    const short* Vb = vtb + ((size_t)(n * 2 + kg) * 64) * 512;

    auto stage = [&](int jt, int buf) {
        int c0 = jt * 64;
        int chunk = wave * 64 + lane;    // 0..511
        int row = chunk >> 3, kc = chunk & 7;
        int sw = (kc ^ (row & 7)) << 3;
        gload16(Kb + (size_t)(c0 + row) * 64 + sw, &Kt[buf][wave * 512]);
        gload16(Vb + (size_t)row * 512 + c0 + sw, &Vt[buf][wave * 512]);
    };

    stage(0, 0);
    int buf = 0;
    #pragma unroll
    for (int ph = 0; ph < 2; ++ph) {
        int rowb = (ph ? (7 - c) : c) * 64 + u * 16;
        int NTp = ph ? (8 - c) : (c + 1);
        bf16x8 qf[2];
        #pragma unroll
        for (int ks = 0; ks < 2; ++ks)
            qf[ks] = *(const bf16x8*)(Qb + (size_t)(rowb + cl) * 64 + ks * 32 + (g << 3));
        f32x4 Oc[4] = {};
        float mrow = -1e30f, lrow = 0.f;
        bool rv = pm[n * 512 + rowb + cl] != 0;
        int rq = rowb + cl;                      // this lane's absolute q row

        for (int jt = 0; jt < NTp; ++jt) {
            __syncthreads();                     // drains vmcnt -> Kt/Vt[buf] ready
            if (jt + 1 < NTp) stage(jt + 1, buf ^ 1);
            else if (ph == 0) stage(0, buf ^ 1); // prefetch phase B's first tile
            int c0 = jt * 64;
            const short* Kc = Kt[buf];
            const short* Vc = Vt[buf];
            buf ^= 1;

            // S' = K Q (swapped): sacc[nf][rg] = S[kv = c0+nf*16+g*4+rg][q = rowb+cl]
            f32x4 sacc[4] = {};
            #pragma unroll
            for (int ks = 0; ks < 2; ++ks) {
                #pragma unroll
                for (int nf = 0; nf < 4; ++nf) {
                    int row = nf * 16 + cl;
                    int kc = ks * 4 + g;
                    bf16x8 kf = *(const bf16x8*)(Kc + row * 64 + ((kc ^ (row & 7)) << 3));
                    sacc[nf] = __builtin_amdgcn_mfma_f32_16x16x32_bf16(kf, qf[ks], sacc[nf], 0, 0, 0);
                }
            }

            // mask (diag tile only) + online softmax (per-lane q-row) + swizzled P store
            const bool diag = (jt == NTp - 1);
            float rmax = -1e30f;
            if (diag) {
                #pragma unroll
                for (int nf = 0; nf < 4; ++nf)
                    #pragma unroll
                    for (int rg = 0; rg < 4; ++rg) {
                        int kv = c0 + nf * 16 + g * 4 + rg;
                        float sv = sacc[nf][rg];
                        sv = (kv <= rq && rv) ? sv : NEG_INF_F;
                        sacc[nf][rg] = sv;
                        rmax = fmaxf(rmax, sv);
                    }
            } else {
                #pragma unroll
                for (int nf = 0; nf < 4; ++nf)
                    #pragma unroll
                    for (int rg = 0; rg < 4; ++rg)
                        rmax = fmaxf(rmax, sacc[nf][rg]);
            }
            rmax = fmaxf(rmax, __shfl_xor(rmax, 16));
            rmax = fmaxf(rmax, __shfl_xor(rmax, 32));
            float mold = mrow;
            int defer = __all(rmax - mold <= 8.0f);  // wave-uniform
            float mnew = defer ? mold : fmaxf(mold, rmax);
            mrow = mnew;
            float rsum = 0.f;
            #pragma unroll
            for (int nf = 0; nf < 4; ++nf) {
                s16x4 pk;
                #pragma unroll
                for (int rg = 0; rg < 4; ++rg) {
                    float p = exp2f(sacc[nf][rg] - mnew);
                    rsum += p;
                    ((short*)&pk)[rg] = f2bf_hw(p);
                }
                *(s16x4*)(&Pws[wave][cl * 64 + ((((nf << 1) + (g >> 1)) ^ (cl & 7)) << 3) + ((g & 1) << 2)]) = pk;
            }
            rsum += __shfl_xor(rsum, 16);
            rsum += __shfl_xor(rsum, 32);
            if (defer) {
                lrow += rsum;
            } else {
                float alpha = exp2f(mold - mnew);
                lrow = lrow * alpha + rsum;
                #pragma unroll
                for (int rg = 0; rg < 4; ++rg) {
                    float av = __shfl(alpha, (lane & 48) + (g << 2) + rg);
                    #pragma unroll
                    for (int nf = 0; nf < 4; ++nf) Oc[nf][rg] *= av;
                }
            }

            // O += P V   (A = P rows q, B = V^T rows d)
            #pragma unroll
            for (int ks = 0; ks < 2; ++ks) {
                bf16x8 pf = *(const bf16x8*)(&Pws[wave][cl * 64 + (((ks * 4 + g) ^ (cl & 7)) << 3)]);
                #pragma unroll
                for (int nf = 0; nf < 4; ++nf) {
                    int row = nf * 16 + cl;
                    int kc = ks * 4 + g;
                    bf16x8 vf = *(const bf16x8*)(Vc + row * 64 + ((kc ^ (row & 7)) << 3));
                    Oc[nf] = __builtin_amdgcn_mfma_f32_16x16x32_bf16(pf, vf, Oc[nf], 0, 0, 0);
                }
            }
        }

        // phase epilogue: O /= l (l redistributed to PV layout), write bf16
        #pragma unroll
        for (int rg = 0; rg < 4; ++rg) {
            float li = __shfl(lrow, (lane & 48) + (g << 2) + rg);
            float inv = 1.0f / li;
            int r = rowb + g * 4 + rg;
            size_t base = ((size_t)n * 512 + r) * 512 + h * 64;
            #pragma unroll
            for (int nf = 0; nf < 4; ++nf)
                ao[base + nf * 16 + cl] = f2bf_hw(Oc[nf][rg] * inv);
        }
    }
}

// ---------------- kernel 3: output projection + (B,T,S,D) scatter ----------------
__global__ __launch_bounds__(256) void k_gemm_out(
    const short* __restrict__ ao, const short* __restrict__ ow, float* __restrict__ out)
{
    __shared__ short As0[128 * 32], As1[128 * 32], Bs0[128 * 32], Bs1[128 * 32];
    int tid = threadIdx.x, wave = tid >> 6, lane = tid & 63;
    int bm = blockIdx.x, bn = blockIdx.y;
    f32x4 acc[4][4] = {};
    gemm_mainloop_db(ao + (size_t)bm * 128 * 512, ow + (size_t)bn * 128 * 512, 512,
                     As0, As1, Bs0, Bs1, wave, lane, acc);

    int wr = (wave >> 1) * 64, wc = (wave & 1) * 64;
    #pragma unroll
    for (int mf = 0; mf < 4; ++mf) {
        #pragma unroll
        for (int rg = 0; rg < 4; ++rg) {
            int r = bm * 128 + wr + mf * 16 + ((lane >> 4) << 2) + rg;
            int n = r >> 9, t = r & 511, b = n >> 4, s = n & 15;
            size_t obase = ((size_t)((b * 512 + t) * 16 + s)) * 512;
            #pragma unroll
            for (int nf = 0; nf < 4; ++nf) {
                int ccc = bn * 128 + wc + nf * 16 + (lane & 15);
                out[obase + ccc] = acc[mf][nf][rg];
            }
        }
    }
}

// ---------------- launch ----------------
extern "C" void kernel_launch(void* const* d_in, const int* in_sizes, int n_in,
                              void* d_out, int out_size, void* d_ws, size_t ws_size,
                              hipStream_t stream) {
    (void)in_sizes; (void)n_in; (void)out_size; (void)ws_size;
    const float* x    = (const float*)d_in[0];
    const int*   pmsk = (const int*)d_in[1];
    const float* qkvw = (const float*)d_in[2];
    const float* owf  = (const float*)d_in[3];
    char* ws = (char*)d_ws;
    short* xt   = (short*)(ws + 0);          // 16,777,216 B (reused as attn-out)
    short* qw   = (short*)(ws + 16777216);   //    786,432 B
    short* ow   = (short*)(ws + 17563648);   //    524,288 B
    float* cosT = (float*)(ws + 18087936);   //     65,536 B
    float* sinT = (float*)(ws + 18153472);   //     65,536 B
    short* qbuf = (short*)(ws + 18219008);   // 16,777,216 B
    short* kbuf = (short*)(ws + 34996224);   //  4,194,304 B
    short* vtbuf= (short*)(ws + 39190528);   //  4,194,304 B  (end 43,384,832)
    short* aobuf = xt;                       // xt dead after GEMM1 -> reuse
    float* out = (float*)d_out;

    k_convert<<<dim3(17792), dim3(128), 0, stream>>>(x, qkvw, owf, xt, qw, ow, cosT, sinT);
    k_gemm_qkv<<<dim3(128, 6), dim3(256), 0, stream>>>(xt, qw, cosT, sinT, qbuf, kbuf, vtbuf);
    k_attn<<<dim3(512), dim3(512), 0, stream>>>(qbuf, kbuf, vtbuf, pmsk, aobuf);
    k_gemm_out<<<dim3(128, 4), dim3(256), 0, stream>>>(aobuf, ow, out);
}